// Round 1
// baseline (320.023 us; speedup 1.0000x reference)
//
#include <hip/hip_runtime.h>
#include <stdint.h>
#include <stddef.h>

#define B_ 2048
#define D_ 4096
#define E_ 512
#define N_ 8192

typedef unsigned short ushort_t;
typedef __attribute__((ext_vector_type(8))) short short8;
typedef __attribute__((ext_vector_type(4))) float floatx4;
typedef __attribute__((ext_vector_type(4))) unsigned short ushort4_t;

__device__ __forceinline__ void async_load16(const void* g, void* l) {
  __builtin_amdgcn_global_load_lds((__attribute__((address_space(1))) void*)(g),
                                   (__attribute__((address_space(3))) void*)(l), 16, 0, 0);
}

__device__ __forceinline__ ushort_t f2bf(float f) {
  unsigned int u = __float_as_uint(f);
  unsigned int r = (u + 0x7fffu + ((u >> 16) & 1u)) >> 16;
  return (ushort_t)r;
}
__device__ __forceinline__ float bf2f(ushort_t h) {
  return __uint_as_float(((unsigned int)h) << 16);
}

// ---------------- BatchNorm stats ----------------
__global__ void bn_partial(const float* __restrict__ vf,
                           float* __restrict__ psum, float* __restrict__ psq) {
  int d = blockIdx.x * 256 + threadIdx.x;   // column
  int chunk = blockIdx.y;                    // 32 chunks of 64 rows
  float s = 0.f, q = 0.f;
  int r0 = chunk * 64;
  for (int r = r0; r < r0 + 64; ++r) {
    float v = vf[(size_t)r * D_ + d];
    s += v; q += v * v;
  }
  psum[chunk * D_ + d] = s;
  psq[chunk * D_ + d]  = q;
}

__global__ void bn_finalize(const float* __restrict__ psum, const float* __restrict__ psq,
                            const float* __restrict__ gamma, const float* __restrict__ beta,
                            float* __restrict__ scale, float* __restrict__ shift) {
  int d = blockIdx.x * 256 + threadIdx.x;
  float s = 0.f, q = 0.f;
  for (int c = 0; c < 32; ++c) { s += psum[c * D_ + d]; q += psq[c * D_ + d]; }
  float mean = s * (1.0f / B_);
  float var  = q * (1.0f / B_) - mean * mean;
  float sc = gamma[d] * rsqrtf(var + 1e-5f);
  scale[d] = sc;
  shift[d] = beta[d] - mean * sc;
}

// ---------------- p_e: rowwise cosine(vfn, p_wfs) ----------------
__global__ void pe_kernel(const float* __restrict__ vf, const float* __restrict__ p,
                          const float* __restrict__ scale, const float* __restrict__ shift,
                          float* __restrict__ pe) {
  int v = blockIdx.x;
  const floatx4* vf4 = (const floatx4*)(vf + (size_t)v * D_);
  const floatx4* p4  = (const floatx4*)(p  + (size_t)v * D_);
  const floatx4* sc4 = (const floatx4*)scale;
  const floatx4* sh4 = (const floatx4*)shift;
  float sd = 0.f, sa = 0.f, sb = 0.f;
  for (int i = threadIdx.x; i < D_ / 4; i += 256) {
    floatx4 x = vf4[i], y = p4[i], s = sc4[i], t = sh4[i];
#pragma unroll
    for (int j = 0; j < 4; ++j) {
      float xn = x[j] * s[j] + t[j];
      sd += xn * y[j]; sa += xn * xn; sb += y[j] * y[j];
    }
  }
  for (int off = 32; off; off >>= 1) {
    sd += __shfl_down(sd, off); sa += __shfl_down(sa, off); sb += __shfl_down(sb, off);
  }
  __shared__ float red[3][4];
  int w = threadIdx.x >> 6, l = threadIdx.x & 63;
  if (l == 0) { red[0][w] = sd; red[1][w] = sa; red[2][w] = sb; }
  __syncthreads();
  if (threadIdx.x == 0) {
    sd = red[0][0] + red[0][1] + red[0][2] + red[0][3];
    sa = red[1][0] + red[1][1] + red[1][2] + red[1][3];
    sb = red[2][0] + red[2][1] + red[2][2] + red[2][3];
    float na = fmaxf(sqrtf(sa), 1e-8f), nb = fmaxf(sqrtf(sb), 1e-8f);
    pe[v] = sd / (na * nb);
  }
}

// ---------------- casts ----------------
__global__ void cast_vfn(const float* __restrict__ vf, const float* __restrict__ scale,
                         const float* __restrict__ shift, ushort_t* __restrict__ out) {
  size_t i = ((size_t)blockIdx.x * 256 + threadIdx.x) * 4;
  int d = (int)(i & (D_ - 1));
  floatx4 x = *(const floatx4*)(vf + i);
  floatx4 s = *(const floatx4*)(scale + d);
  floatx4 t = *(const floatx4*)(shift + d);
  ushort4_t o;
#pragma unroll
  for (int j = 0; j < 4; ++j) o[j] = f2bf(x[j] * s[j] + t[j]);
  *(ushort4_t*)(out + i) = o;
}

__global__ void cast_w(const float* __restrict__ W, ushort_t* __restrict__ out) {
  size_t i = ((size_t)blockIdx.x * 256 + threadIdx.x) * 4;
  floatx4 x = *(const floatx4*)(W + i);
  ushort4_t o;
#pragma unroll
  for (int j = 0; j < 4; ++j) o[j] = f2bf(x[j]);
  *(ushort4_t*)(out + i) = o;
}

// n_wfs rows -> bf16 + inverse norms. 128 threads/block, one block per row.
__global__ void nw_kernel(const float* __restrict__ nw, ushort_t* __restrict__ nwb,
                          float* __restrict__ inv_nw) {
  int n = blockIdx.x;
  int t = threadIdx.x;
  floatx4 x = ((const floatx4*)(nw + (size_t)n * E_))[t];
  float s = x[0]*x[0] + x[1]*x[1] + x[2]*x[2] + x[3]*x[3];
  ushort4_t o;
#pragma unroll
  for (int j = 0; j < 4; ++j) o[j] = f2bf(x[j]);
  ((ushort4_t*)(nwb + (size_t)n * E_))[t] = o;
  for (int off = 32; off; off >>= 1) s += __shfl_down(s, off);
  __shared__ float r2[2];
  if ((t & 63) == 0) r2[t >> 6] = s;
  __syncthreads();
  if (t == 0) inv_nw[n] = 1.f / fmaxf(sqrtf(r2[0] + r2[1]), 1e-8f);
}

// emb (bf16) row inverse norms. 128 threads, one block per row.
__global__ void emb_norm(const ushort_t* __restrict__ emb, float* __restrict__ inv_emb) {
  int v = blockIdx.x;
  int t = threadIdx.x;
  ushort4_t x = ((const ushort4_t*)(emb + (size_t)v * E_))[t];
  float s = 0.f;
#pragma unroll
  for (int j = 0; j < 4; ++j) { float f = bf2f(x[j]); s += f * f; }
  for (int off = 32; off; off >>= 1) s += __shfl_down(s, off);
  __shared__ float r2[2];
  if ((t & 63) == 0) r2[t >> 6] = s;
  __syncthreads();
  if (t == 0) inv_emb[v] = 1.f / fmaxf(sqrtf(r2[0] + r2[1]), 1e-8f);
}

// ---------------- MFMA gemm core (A row-major [M,K], Bt row-major [N,K]) ----------------
// Verified gfx950 16x16x32 bf16 layout: a-frag A[m=lane&15][k=quad*8+j],
// b-frag Bt[n=lane&15][k=quad*8+j], C/D: col=lane&15, row=quad*4+reg.
template <int BM, int BN, int BK, int WROWS, int WCOLS, int MT, int NT>
__device__ __forceinline__ void gemm_core(const ushort_t* __restrict__ A,
                                          const ushort_t* __restrict__ Bt, int K,
                                          int bm0, int bn0,
                                          ushort_t* As, ushort_t* Bs,
                                          floatx4 (&acc)[MT][NT]) {
  const int tid = threadIdx.x, w = tid >> 6, l = tid & 63;
  constexpr int ISS = BM * BK / 2048;   // 256 threads x 8 elems per issue
  const int wr = w / WCOLS, wc = w % WCOLS;
  const int m16 = l & 15, q = l >> 4;

  for (int k0 = 0; k0 < K; k0 += BK) {
#pragma unroll
    for (int i = 0; i < ISS; ++i) {
      int e = i * 2048 + tid * 8;
      int row = e / BK, col = e % BK;
      async_load16(A + (size_t)(bm0 + row) * K + (k0 + col), &As[i * 2048 + w * 512]);
    }
#pragma unroll
    for (int i = 0; i < ISS; ++i) {
      int e = i * 2048 + tid * 8;
      int row = e / BK, col = e % BK;
      async_load16(Bt + (size_t)(bn0 + row) * K + (k0 + col), &Bs[i * 2048 + w * 512]);
    }
    __syncthreads();
#pragma unroll
    for (int kc = 0; kc < BK / 32; ++kc) {
      short8 af[MT], bf[NT];
#pragma unroll
      for (int i = 0; i < MT; ++i)
        af[i] = *(const short8*)&As[(wr * (MT * 16) + i * 16 + m16) * BK + kc * 32 + q * 8];
#pragma unroll
      for (int j = 0; j < NT; ++j)
        bf[j] = *(const short8*)&Bs[(wc * (NT * 16) + j * 16 + m16) * BK + kc * 32 + q * 8];
#pragma unroll
      for (int i = 0; i < MT; ++i)
#pragma unroll
        for (int j = 0; j < NT; ++j)
          acc[i][j] = __builtin_amdgcn_mfma_f32_16x16x32_bf16(af[i], bf[j], acc[i][j], 0, 0, 0);
    }
    __syncthreads();
  }
}

// GEMM1: emb = relu(vfn @ W^T + b), 64x64 tiles (256 blocks for CU coverage)
__global__ __launch_bounds__(256) void gemm1_kernel(const ushort_t* __restrict__ A,
                                                    const ushort_t* __restrict__ Bt,
                                                    const float* __restrict__ bias,
                                                    ushort_t* __restrict__ C) {
  __shared__ __align__(16) ushort_t As[64 * 128];
  __shared__ __align__(16) ushort_t Bs[64 * 128];
  floatx4 acc[2][2] = {};
  int bm0 = blockIdx.y * 64, bn0 = blockIdx.x * 64;
  gemm_core<64, 64, 128, 2, 2, 2, 2>(A, Bt, D_, bm0, bn0, As, Bs, acc);
  int tid = threadIdx.x, w = tid >> 6, l = tid & 63, m16 = l & 15, q = l >> 4;
  int wr = w >> 1, wc = w & 1;
#pragma unroll
  for (int i = 0; i < 2; ++i)
#pragma unroll
    for (int j = 0; j < 2; ++j) {
      int col = bn0 + wc * 32 + j * 16 + m16;
      float bb = bias[col];
#pragma unroll
      for (int r = 0; r < 4; ++r) {
        int row = bm0 + wr * 32 + i * 16 + q * 4 + r;
        float v = fmaxf(acc[i][j][r] + bb, 0.f);
        C[(size_t)row * E_ + col] = f2bf(v);
      }
    }
}

// GEMM2: n_e = (emb @ nw^T) * inv_emb[row] * inv_nw[col], 128x128 tiles (1024 blocks)
__global__ __launch_bounds__(256) void gemm2_kernel(const ushort_t* __restrict__ A,
                                                    const ushort_t* __restrict__ Bt,
                                                    const float* __restrict__ inv_a,
                                                    const float* __restrict__ inv_b,
                                                    float* __restrict__ out) {
  __shared__ __align__(16) ushort_t As[128 * 64];
  __shared__ __align__(16) ushort_t Bs[128 * 64];
  floatx4 acc[4][4] = {};
  int bm0 = blockIdx.y * 128, bn0 = blockIdx.x * 128;
  gemm_core<128, 128, 64, 2, 2, 4, 4>(A, Bt, E_, bm0, bn0, As, Bs, acc);
  int tid = threadIdx.x, w = tid >> 6, l = tid & 63, m16 = l & 15, q = l >> 4;
  int wr = w >> 1, wc = w & 1;
#pragma unroll
  for (int i = 0; i < 4; ++i)
#pragma unroll
    for (int j = 0; j < 4; ++j) {
      int col = bn0 + wc * 64 + j * 16 + m16;
      float ib = inv_b[col];
#pragma unroll
      for (int r = 0; r < 4; ++r) {
        int row = bm0 + wr * 64 + i * 16 + q * 4 + r;
        out[(size_t)row * N_ + col] = acc[i][j][r] * inv_a[row] * ib;
      }
    }
}

// p_e_stack: out2[v*N + n] = pe[v], float4-coalesced
__global__ void fill_pe(const float* __restrict__ pe, float* __restrict__ out2) {
  size_t i = (size_t)blockIdx.x * 256 + threadIdx.x;  // float4 index, total B*N/4
  int v = (int)(i >> 11);                             // N/4 = 2048 float4 per row
  float p = pe[v];
  floatx4 o = {p, p, p, p};
  ((floatx4*)out2)[i] = o;
}

extern "C" void kernel_launch(void* const* d_in, const int* in_sizes, int n_in,
                              void* d_out, int out_size, void* d_ws, size_t ws_size,
                              hipStream_t stream) {
  (void)in_sizes; (void)n_in; (void)out_size; (void)ws_size;
  const float* vf    = (const float*)d_in[0];
  const float* p_wfs = (const float*)d_in[1];
  const float* n_wfs = (const float*)d_in[2];
  const float* gamma = (const float*)d_in[3];
  const float* beta  = (const float*)d_in[4];
  const float* W     = (const float*)d_in[5];
  const float* bias  = (const float*)d_in[6];
  float* out = (float*)d_out;

  char* ws = (char*)d_ws;
  float* psum    = (float*)ws;  ws += (size_t)32 * D_ * 4;
  float* psq     = (float*)ws;  ws += (size_t)32 * D_ * 4;
  float* scale   = (float*)ws;  ws += (size_t)D_ * 4;
  float* shift   = (float*)ws;  ws += (size_t)D_ * 4;
  float* pe      = (float*)ws;  ws += (size_t)B_ * 4;
  float* inv_nw  = (float*)ws;  ws += (size_t)N_ * 4;
  float* inv_emb = (float*)ws;  ws += (size_t)B_ * 4;
  ushort_t* vfn  = (ushort_t*)ws;  ws += (size_t)B_ * D_ * 2;
  ushort_t* wb   = (ushort_t*)ws;  ws += (size_t)E_ * D_ * 2;
  ushort_t* nwb  = (ushort_t*)ws;  ws += (size_t)N_ * E_ * 2;
  ushort_t* emb  = (ushort_t*)ws;  ws += (size_t)B_ * E_ * 2;

  bn_partial<<<dim3(D_ / 256, 32), 256, 0, stream>>>(vf, psum, psq);
  bn_finalize<<<D_ / 256, 256, 0, stream>>>(psum, psq, gamma, beta, scale, shift);
  pe_kernel<<<B_, 256, 0, stream>>>(vf, p_wfs, scale, shift, pe);
  cast_vfn<<<(B_ * D_ / 4) / 256, 256, 0, stream>>>(vf, scale, shift, vfn);
  cast_w<<<(E_ * D_ / 4) / 256, 256, 0, stream>>>(W, wb);
  nw_kernel<<<N_, 128, 0, stream>>>(n_wfs, nwb, inv_nw);
  gemm1_kernel<<<dim3(E_ / 64, B_ / 64), 256, 0, stream>>>(vfn, wb, bias, emb);
  emb_norm<<<B_, 128, 0, stream>>>(emb, inv_emb);
  gemm2_kernel<<<dim3(N_ / 128, B_ / 128), 256, 0, stream>>>(emb, nwb, inv_emb, inv_nw, out);
  fill_pe<<<(B_ * N_ / 4) / 256, 256, 0, stream>>>(pe, out + (size_t)B_ * N_);
}

// Round 2
// 283.599 us; speedup vs baseline: 1.1284x; 1.1284x over previous
//
#include <hip/hip_runtime.h>
#include <stdint.h>
#include <stddef.h>

#define B_ 2048
#define D_ 4096
#define E_ 512
#define N_ 8192
#define SPLITK 4

typedef unsigned short ushort_t;
typedef __attribute__((ext_vector_type(8))) short short8;
typedef __attribute__((ext_vector_type(4))) float floatx4;
typedef __attribute__((ext_vector_type(4))) unsigned short ushort4_t;

__device__ __forceinline__ void async_load16(const void* g, void* l) {
  __builtin_amdgcn_global_load_lds((__attribute__((address_space(1))) void*)(g),
                                   (__attribute__((address_space(3))) void*)(l), 16, 0, 0);
}

__device__ __forceinline__ ushort_t f2bf(float f) {
  unsigned int u = __float_as_uint(f);
  unsigned int r = (u + 0x7fffu + ((u >> 16) & 1u)) >> 16;
  return (ushort_t)r;
}
__device__ __forceinline__ float bf2f(ushort_t h) {
  return __uint_as_float(((unsigned int)h) << 16);
}

// ---------------- BatchNorm stats ----------------
__global__ void bn_partial(const float* __restrict__ vf,
                           float* __restrict__ psum, float* __restrict__ psq) {
  int d = blockIdx.x * 256 + threadIdx.x;
  int chunk = blockIdx.y;
  float s = 0.f, q = 0.f;
  int r0 = chunk * 64;
  for (int r = r0; r < r0 + 64; ++r) {
    float v = vf[(size_t)r * D_ + d];
    s += v; q += v * v;
  }
  psum[chunk * D_ + d] = s;
  psq[chunk * D_ + d]  = q;
}

__global__ void bn_finalize(const float* __restrict__ psum, const float* __restrict__ psq,
                            const float* __restrict__ gamma, const float* __restrict__ beta,
                            float* __restrict__ scale, float* __restrict__ shift) {
  int d = blockIdx.x * 256 + threadIdx.x;
  float s = 0.f, q = 0.f;
  for (int c = 0; c < 32; ++c) { s += psum[c * D_ + d]; q += psq[c * D_ + d]; }
  float mean = s * (1.0f / B_);
  float var  = q * (1.0f / B_) - mean * mean;
  float sc = gamma[d] * rsqrtf(var + 1e-5f);
  scale[d] = sc;
  shift[d] = beta[d] - mean * sc;
}

// ---------------- fused: p_e cosine + vfn bf16 cast ----------------
// One block per row: reads vf+p_wfs once, writes bf16 vfn, reduces cosine.
__global__ __launch_bounds__(256) void pe_cast(const float* __restrict__ vf,
                                               const float* __restrict__ p,
                                               const float* __restrict__ scale,
                                               const float* __restrict__ shift,
                                               ushort_t* __restrict__ vfn,
                                               float* __restrict__ pe) {
  int v = blockIdx.x;
  const floatx4* vf4 = (const floatx4*)(vf + (size_t)v * D_);
  const floatx4* p4  = (const floatx4*)(p  + (size_t)v * D_);
  const floatx4* sc4 = (const floatx4*)scale;
  const floatx4* sh4 = (const floatx4*)shift;
  ushort_t* vrow = vfn + (size_t)v * D_;
  float sd = 0.f, sa = 0.f, sb = 0.f;
  for (int i = threadIdx.x; i < D_ / 4; i += 256) {
    floatx4 x = vf4[i], y = p4[i], s = sc4[i], t = sh4[i];
    ushort4_t o;
#pragma unroll
    for (int j = 0; j < 4; ++j) {
      float xn = x[j] * s[j] + t[j];
      o[j] = f2bf(xn);
      sd += xn * y[j]; sa += xn * xn; sb += y[j] * y[j];
    }
    *(ushort4_t*)(vrow + i * 4) = o;
  }
  for (int off = 32; off; off >>= 1) {
    sd += __shfl_down(sd, off); sa += __shfl_down(sa, off); sb += __shfl_down(sb, off);
  }
  __shared__ float red[3][4];
  int w = threadIdx.x >> 6, l = threadIdx.x & 63;
  if (l == 0) { red[0][w] = sd; red[1][w] = sa; red[2][w] = sb; }
  __syncthreads();
  if (threadIdx.x == 0) {
    sd = red[0][0] + red[0][1] + red[0][2] + red[0][3];
    sa = red[1][0] + red[1][1] + red[1][2] + red[1][3];
    sb = red[2][0] + red[2][1] + red[2][2] + red[2][3];
    float na = fmaxf(sqrtf(sa), 1e-8f), nb = fmaxf(sqrtf(sb), 1e-8f);
    pe[v] = sd / (na * nb);
  }
}

__global__ void cast_w(const float* __restrict__ W, ushort_t* __restrict__ out) {
  size_t i = ((size_t)blockIdx.x * 256 + threadIdx.x) * 4;
  floatx4 x = *(const floatx4*)(W + i);
  ushort4_t o;
#pragma unroll
  for (int j = 0; j < 4; ++j) o[j] = f2bf(x[j]);
  *(ushort4_t*)(out + i) = o;
}

// n_wfs rows -> bf16 + inverse norms
__global__ void nw_kernel(const float* __restrict__ nw, ushort_t* __restrict__ nwb,
                          float* __restrict__ inv_nw) {
  int n = blockIdx.x;
  int t = threadIdx.x;
  floatx4 x = ((const floatx4*)(nw + (size_t)n * E_))[t];
  float s = x[0]*x[0] + x[1]*x[1] + x[2]*x[2] + x[3]*x[3];
  ushort4_t o;
#pragma unroll
  for (int j = 0; j < 4; ++j) o[j] = f2bf(x[j]);
  ((ushort4_t*)(nwb + (size_t)n * E_))[t] = o;
  for (int off = 32; off; off >>= 1) s += __shfl_down(s, off);
  __shared__ float r2[2];
  if ((t & 63) == 0) r2[t >> 6] = s;
  __syncthreads();
  if (t == 0) inv_nw[n] = 1.f / fmaxf(sqrtf(r2[0] + r2[1]), 1e-8f);
}

// ---------------- MFMA gemm core ----------------
// Verified gfx950 16x16x32 bf16 layout: a-frag A[m=lane&15][k=quad*8+j],
// b-frag Bt[n=lane&15][k=quad*8+j], C/D: col=lane&15, row=quad*4+reg.
template <int BM, int BN, int BK, int WCOLS, int MT, int NT>
__device__ __forceinline__ void gemm_core(const ushort_t* __restrict__ A,
                                          const ushort_t* __restrict__ Bt, int K,
                                          int kb, int ke, int bm0, int bn0,
                                          ushort_t* As, ushort_t* Bs,
                                          floatx4 (&acc)[MT][NT]) {
  const int tid = threadIdx.x, w = tid >> 6, l = tid & 63;
  constexpr int ISS = BM * BK / 2048;   // 256 threads x 8 bf16 per issue
  const int wr = w / WCOLS, wc = w % WCOLS;
  const int m16 = l & 15, q = l >> 4;

  for (int k0 = kb; k0 < ke; k0 += BK) {
#pragma unroll
    for (int i = 0; i < ISS; ++i) {
      int e = i * 2048 + tid * 8;
      int row = e / BK, col = e % BK;
      async_load16(A + (size_t)(bm0 + row) * K + (k0 + col), &As[i * 2048 + w * 512]);
    }
#pragma unroll
    for (int i = 0; i < ISS; ++i) {
      int e = i * 2048 + tid * 8;
      int row = e / BK, col = e % BK;
      async_load16(Bt + (size_t)(bn0 + row) * K + (k0 + col), &Bs[i * 2048 + w * 512]);
    }
    __syncthreads();
#pragma unroll
    for (int kc = 0; kc < BK / 32; ++kc) {
      short8 af[MT], bf[NT];
#pragma unroll
      for (int i = 0; i < MT; ++i)
        af[i] = *(const short8*)&As[(wr * (MT * 16) + i * 16 + m16) * BK + kc * 32 + q * 8];
#pragma unroll
      for (int j = 0; j < NT; ++j)
        bf[j] = *(const short8*)&Bs[(wc * (NT * 16) + j * 16 + m16) * BK + kc * 32 + q * 8];
#pragma unroll
      for (int i = 0; i < MT; ++i)
#pragma unroll
        for (int j = 0; j < NT; ++j)
          acc[i][j] = __builtin_amdgcn_mfma_f32_16x16x32_bf16(af[i], bf[j], acc[i][j], 0, 0, 0);
    }
    __syncthreads();
  }
}

// GEMM1 split-K: partial[s] = vfn @ W^T over K-range s. 64x64 tiles, 1024 blocks.
__global__ __launch_bounds__(256) void gemm1_splitk(const ushort_t* __restrict__ A,
                                                    const ushort_t* __restrict__ Bt,
                                                    float* __restrict__ partial) {
  __shared__ __align__(16) ushort_t As[64 * 64];
  __shared__ __align__(16) ushort_t Bs[64 * 64];
  floatx4 acc[2][2] = {};
  int bm0 = blockIdx.y * 64, bn0 = blockIdx.x * 64, s = blockIdx.z;
  int kb = s * (D_ / SPLITK);
  gemm_core<64, 64, 64, 2, 2, 2>(A, Bt, D_, kb, kb + D_ / SPLITK, bm0, bn0, As, Bs, acc);
  int tid = threadIdx.x, w = tid >> 6, l = tid & 63, m16 = l & 15, q = l >> 4;
  int wr = w >> 1, wc = w & 1;
  float* out = partial + (size_t)s * B_ * E_;
#pragma unroll
  for (int i = 0; i < 2; ++i)
#pragma unroll
    for (int j = 0; j < 2; ++j) {
      int col = bn0 + wc * 32 + j * 16 + m16;
#pragma unroll
      for (int r = 0; r < 4; ++r) {
        int row = bm0 + wr * 32 + i * 16 + q * 4 + r;
        out[(size_t)row * E_ + col] = acc[i][j][r];
      }
    }
}

// Reduce splits + bias + ReLU + bf16 cast + row inv-norm (absorbs emb_norm).
// One block (128 threads) per row.
__global__ __launch_bounds__(128) void gemm1_reduce(const float* __restrict__ partial,
                                                    const float* __restrict__ bias,
                                                    ushort_t* __restrict__ emb,
                                                    float* __restrict__ inv_emb) {
  int row = blockIdx.x, t = threadIdx.x;
  floatx4 v = {0.f, 0.f, 0.f, 0.f};
#pragma unroll
  for (int s = 0; s < SPLITK; ++s)
    v += *(const floatx4*)&partial[(size_t)s * B_ * E_ + (size_t)row * E_ + t * 4];
  floatx4 bb = *(const floatx4*)&bias[t * 4];
  ushort4_t o;
  float sumsq = 0.f;
#pragma unroll
  for (int j = 0; j < 4; ++j) {
    float f = fmaxf(v[j] + bb[j], 0.f);
    o[j] = f2bf(f);
    float fb = bf2f(o[j]);          // norm of the bf16-rounded emb, matching gemm2 input
    sumsq += fb * fb;
  }
  *(ushort4_t*)(emb + (size_t)row * E_ + t * 4) = o;
  for (int off = 32; off; off >>= 1) sumsq += __shfl_down(sumsq, off);
  __shared__ float r2[2];
  if ((t & 63) == 0) r2[t >> 6] = sumsq;
  __syncthreads();
  if (t == 0) inv_emb[row] = 1.f / fmaxf(sqrtf(r2[0] + r2[1]), 1e-8f);
}

// GEMM2: n_e = (emb @ nw^T) * inv_emb[row] * inv_nw[col]; also fills p_e_stack.
__global__ __launch_bounds__(256) void gemm2_kernel(const ushort_t* __restrict__ A,
                                                    const ushort_t* __restrict__ Bt,
                                                    const float* __restrict__ inv_a,
                                                    const float* __restrict__ inv_b,
                                                    const float* __restrict__ pe,
                                                    float* __restrict__ out) {
  __shared__ __align__(16) ushort_t As[128 * 64];
  __shared__ __align__(16) ushort_t Bs[128 * 64];
  floatx4 acc[4][4] = {};
  int bm0 = blockIdx.y * 128, bn0 = blockIdx.x * 128;
  gemm_core<128, 128, 64, 2, 4, 4>(A, Bt, E_, 0, E_, bm0, bn0, As, Bs, acc);
  int tid = threadIdx.x, w = tid >> 6, l = tid & 63, m16 = l & 15, q = l >> 4;
  int wr = w >> 1, wc = w & 1;
  float* out2 = out + (size_t)B_ * N_;
  float ibv[4];
#pragma unroll
  for (int j = 0; j < 4; ++j) ibv[j] = inv_b[bn0 + wc * 64 + j * 16 + m16];
#pragma unroll
  for (int i = 0; i < 4; ++i)
#pragma unroll
    for (int r = 0; r < 4; ++r) {
      int row = bm0 + wr * 64 + i * 16 + q * 4 + r;
      float ia = inv_a[row];
      float pv = pe[row];
      size_t base = (size_t)row * N_ + bn0 + wc * 64 + m16;
#pragma unroll
      for (int j = 0; j < 4; ++j) {
        out[base + j * 16]  = acc[i][j][r] * ia * ibv[j];
        out2[base + j * 16] = pv;
      }
    }
}

extern "C" void kernel_launch(void* const* d_in, const int* in_sizes, int n_in,
                              void* d_out, int out_size, void* d_ws, size_t ws_size,
                              hipStream_t stream) {
  (void)in_sizes; (void)n_in; (void)out_size; (void)ws_size;
  const float* vf    = (const float*)d_in[0];
  const float* p_wfs = (const float*)d_in[1];
  const float* n_wfs = (const float*)d_in[2];
  const float* gamma = (const float*)d_in[3];
  const float* beta  = (const float*)d_in[4];
  const float* W     = (const float*)d_in[5];
  const float* bias  = (const float*)d_in[6];
  float* out = (float*)d_out;

  char* ws = (char*)d_ws;
  float* psum    = (float*)ws;  ws += (size_t)32 * D_ * 4;
  float* psq     = (float*)ws;  ws += (size_t)32 * D_ * 4;
  float* scale   = (float*)ws;  ws += (size_t)D_ * 4;
  float* shift   = (float*)ws;  ws += (size_t)D_ * 4;
  float* pe      = (float*)ws;  ws += (size_t)B_ * 4;
  float* inv_nw  = (float*)ws;  ws += (size_t)N_ * 4;
  float* inv_emb = (float*)ws;  ws += (size_t)B_ * 4;
  float* partial = (float*)ws;  ws += (size_t)SPLITK * B_ * E_ * 4;
  ushort_t* vfn  = (ushort_t*)ws;  ws += (size_t)B_ * D_ * 2;
  ushort_t* wb   = (ushort_t*)ws;  ws += (size_t)E_ * D_ * 2;
  ushort_t* nwb  = (ushort_t*)ws;  ws += (size_t)N_ * E_ * 2;
  ushort_t* emb  = (ushort_t*)ws;  ws += (size_t)B_ * E_ * 2;

  bn_partial<<<dim3(D_ / 256, 32), 256, 0, stream>>>(vf, psum, psq);
  bn_finalize<<<D_ / 256, 256, 0, stream>>>(psum, psq, gamma, beta, scale, shift);
  pe_cast<<<B_, 256, 0, stream>>>(vf, p_wfs, scale, shift, vfn, pe);
  cast_w<<<(E_ * D_ / 4) / 256, 256, 0, stream>>>(W, wb);
  nw_kernel<<<N_, 128, 0, stream>>>(n_wfs, nwb, inv_nw);
  gemm1_splitk<<<dim3(E_ / 64, B_ / 64, SPLITK), 256, 0, stream>>>(vfn, wb, partial);
  gemm1_reduce<<<B_, 128, 0, stream>>>(partial, bias, emb, inv_emb);
  gemm2_kernel<<<dim3(N_ / 128, B_ / 128), 256, 0, stream>>>(emb, nwb, inv_emb, inv_nw, pe, out);
}